// Round 8
// baseline (1311.074 us; speedup 1.0000x reference)
//
#include <hip/hip_runtime.h>

// LSTM: B=512, T=1000, IN=39, H=64, OUT=48, gate order i,f,g,o.
// R11: dual-pipe weight streaming + one barrier per step.
//   R4-R10 lesson: allocator caps ~92-172 VGPRs -> register-resident weights
//   impossible; every variant re-streams ~104KB/CU/step. So stream it on TWO
//   pipes at once: W_hh (64KB) from LDS (R9's conflict-free gate-quad b128),
//   W_ih (40KB, gate-quad packed into workspace by a pack kernel) from
//   L2/global (shared by all CUs -> L2-resident), W_out k-slice in regs.
//   Broadcasts via v_readlane on lane-distinct h/x regs (VALU pipe, off LDS).
//   ONE barrier/step: partials double-buffered by parity; ALL waves
//   redundantly reduce -> h,c stay in registers (no LDS round-trip on the
//   recurrent critical path). Waves 2/3 store y_{t-1} and stage x.
//   Grid 256 = 1 block/CU, 4 waves, 2 batch rows/block.

#define BB 512
#define TT 1000
#define INF 39
#define HH 64
#define OUTF 48

typedef float v2f __attribute__((ext_vector_type(2)));

__device__ __forceinline__ float sigf(float v)  { return 1.f / (1.f + __expf(-v)); }
__device__ __forceinline__ float tanhx(float v) { return 2.f / (1.f + __expf(-2.f * v)) - 1.f; }

#define RLF(VB, L) __int_as_float(__builtin_amdgcn_readlane((VB), (L)))

// ws layout (float4): [0,2560) = wihG[i*64+j] (i<40, i=39 zero),
//                     [2560,6656) = whhQ[k*64+j]; quads over gates g=0..3.
__global__ void pack_weights(const float* __restrict__ W_ih,
                             const float* __restrict__ W_hh,
                             float4* __restrict__ ws) {
    const int idx = blockIdx.x * 256 + threadIdx.x;
    if (idx < 40 * 64) {
        const int i = idx >> 6, j = idx & 63;
        float4 v = make_float4(0.f, 0.f, 0.f, 0.f);
        if (i < INF) {
            v.x = W_ih[(0 * HH + j) * INF + i];
            v.y = W_ih[(1 * HH + j) * INF + i];
            v.z = W_ih[(2 * HH + j) * INF + i];
            v.w = W_ih[(3 * HH + j) * INF + i];
        }
        ws[idx] = v;
    } else if (idx < 40 * 64 + HH * 64) {
        const int t = idx - 40 * 64;
        const int k = t >> 6, j = t & 63;
        ws[idx] = make_float4(W_hh[(0 * HH + j) * HH + k], W_hh[(1 * HH + j) * HH + k],
                              W_hh[(2 * HH + j) * HH + k], W_hh[(3 * HH + j) * HH + k]);
    }
}

template <bool PACKED>
__global__ __launch_bounds__(256, 1)
void lstm_1bar(const float* __restrict__ x,      // [B,T,IN]
               const float* __restrict__ W_ih,   // [4H, IN]
               const float* __restrict__ W_hh,   // [4H, H]
               const float* __restrict__ b_ih,   // [4H]
               const float* __restrict__ b_hh,   // [4H]
               const float* __restrict__ W_out,  // [OUT, H]
               const float* __restrict__ b_out,  // [OUT]
               const float4* __restrict__ wsq,   // packed weights or nullptr
               float* __restrict__ out)          // [B,T,OUT]
{
    const int tid   = threadIdx.x;
    const int j     = tid & 63;
    const int w     = tid >> 6;
    const int kbase = __builtin_amdgcn_readfirstlane(16 * w);  // k-slice base
    const int ibase = __builtin_amdgcn_readfirstlane(10 * w);  // i-slice base

    __shared__ float4 whhG[HH * 64];         // 64 KB gate-quads of W_hh
    __shared__ float  xsb[2][2][64];         // [par][row][j], j>=39 stays 0
    __shared__ float4 parts[2][4][2][64];    // [par][wave][row][j], 16 KB
    __shared__ float  yparts[2][4][2][64];   // [par][wave][row][j], 4 KB

    // ---- one-time: stage whhG ----
    if constexpr (PACKED) {
        const float4* src = wsq + 40 * 64;
        for (int idx = tid; idx < HH * 64; idx += 256) whhG[idx] = src[idx];
    } else {
        for (int idx = tid; idx < HH * 64; idx += 256) {
            const int k = idx >> 6, jj = idx & 63;
            whhG[idx] = make_float4(W_hh[(0*HH+jj)*HH + k], W_hh[(1*HH+jj)*HH + k],
                                    W_hh[(2*HH+jj)*HH + k], W_hh[(3*HH+jj)*HH + k]);
        }
    }
    ((float*)xsb)[tid] = 0.f;                // zero both parities (256 slots)

    // ---- W_out k-slice in registers (16 floats, historically grantable) ----
    float woa[16];
    float bo = 0.f;
    if (j < OUTF) {
        const float4* p = (const float4*)(W_out + j * HH + kbase);  // 64B-aligned
#pragma unroll
        for (int q = 0; q < 4; ++q) {
            const float4 v = p[q];
            woa[4*q+0] = v.x; woa[4*q+1] = v.y; woa[4*q+2] = v.z; woa[4*q+3] = v.w;
        }
        bo = b_out[j];
    } else {
#pragma unroll
        for (int q = 0; q < 16; ++q) woa[q] = 0.f;
    }

    const float bg0 = b_ih[0*HH+j] + b_hh[0*HH+j];
    const float bg1 = b_ih[1*HH+j] + b_hh[1*HH+j];
    const float bg2 = b_ih[2*HH+j] + b_hh[2*HH+j];
    const float bg3 = b_ih[3*HH+j] + b_hh[3*HH+j];

    const size_t xb0 = (size_t)(2 * blockIdx.x) * TT * INF;
    const size_t xb1 = xb0 + (size_t)TT * INF;
    const size_t ob0 = (size_t)(2 * blockIdx.x) * TT * OUTF;
    const size_t ob1 = ob0 + (size_t)TT * OUTF;

    __syncthreads();                          // whhG + xsb zeros visible

    float xreg = 0.f;
    if (w == 2 && j < INF) { xsb[0][0][j] = x[xb0 + j]; xreg = x[xb0 + INF + j]; }
    if (w == 3 && j < INF) { xsb[0][1][j] = x[xb1 + j]; xreg = x[xb1 + INF + j]; }

    float h0 = 0.f, h1 = 0.f, c0 = 0.f, c1 = 0.f;  // redundant on all waves
    __syncthreads();                          // x_0 staged

    const float4* wkp = whhG + kbase * 64 + j;

    for (int t = 0; t < TT; ++t) {
        const int par = t & 1;

        // ---- lane-distinct x_t; bit views for readlane ----
        const float xr0 = xsb[par][0][j];
        const float xr1 = xsb[par][1][j];
        const int h0b = __float_as_int(h0), h1b = __float_as_int(h1);
        const int x0b = __float_as_int(xr0), x1b = __float_as_int(xr1);

        // ---- W_ih gate-quads from global (L2 pipe), issued early ----
        float4 wv[10];
        if constexpr (PACKED) {
#pragma unroll
            for (int ii = 0; ii < 10; ++ii) wv[ii] = wsq[(ibase + ii) * 64 + j];
        } else {
#pragma unroll
            for (int ii = 0; ii < 10; ++ii) {
                const int i = ibase + ii;
                float4 v = make_float4(0.f, 0.f, 0.f, 0.f);
                if (i < INF) {
                    v.x = W_ih[(0*HH+j)*INF + i]; v.y = W_ih[(1*HH+j)*INF + i];
                    v.z = W_ih[(2*HH+j)*INF + i]; v.w = W_ih[(3*HH+j)*INF + i];
                }
                wv[ii] = v;
            }
        }

        // ---- stage x_{t+1} (writes par^1; readers only touch par) ----
        if (w >= 2 && j < INF) {
            const int r = w - 2;
            xsb[par ^ 1][r][j] = xreg;
            if (t + 2 < TT) xreg = x[(r ? xb1 : xb0) + (size_t)(t + 2) * INF + j];
        }

        // ---- k-slice partial dots: W_hh from LDS, broadcasts via readlane ----
        v2f ac0_01 = {0.f,0.f}, ac0_23 = {0.f,0.f};
        v2f ac1_01 = {0.f,0.f}, ac1_23 = {0.f,0.f};
        v2f yac = {0.f, 0.f};                 // {row0, row1}
#pragma unroll
        for (int K = 0; K < 16; ++K) {
            const float4 wg = wkp[K * 64];
            const float hs0 = RLF(h0b, kbase + K);
            const float hs1 = RLF(h1b, kbase + K);
            ac0_01 += (v2f){wg.x, wg.y} * (v2f){hs0, hs0};
            ac0_23 += (v2f){wg.z, wg.w} * (v2f){hs0, hs0};
            ac1_01 += (v2f){wg.x, wg.y} * (v2f){hs1, hs1};
            ac1_23 += (v2f){wg.z, wg.w} * (v2f){hs1, hs1};
            yac += (v2f){hs0, hs1} * (v2f){woa[K], woa[K]};
        }
#pragma unroll
        for (int ii = 0; ii < 10; ++ii) {
            const float4 wg = wv[ii];
            const float xs0 = RLF(x0b, ibase + ii);
            const float xs1 = RLF(x1b, ibase + ii);
            ac0_01 += (v2f){wg.x, wg.y} * (v2f){xs0, xs0};
            ac0_23 += (v2f){wg.z, wg.w} * (v2f){xs0, xs0};
            ac1_01 += (v2f){wg.x, wg.y} * (v2f){xs1, xs1};
            ac1_23 += (v2f){wg.z, wg.w} * (v2f){xs1, xs1};
        }

        parts[par][w][0][j] = make_float4(ac0_01.x, ac0_01.y, ac0_23.x, ac0_23.y);
        parts[par][w][1][j] = make_float4(ac1_01.x, ac1_01.y, ac1_23.x, ac1_23.y);
        yparts[par][w][0][j] = yac.x;
        yparts[par][w][1][j] = yac.y;
        __syncthreads();                      // the ONLY barrier per step

        // ---- redundant reduce (all waves): h,c stay in registers ----
        {
            const float4 q0 = parts[par][0][0][j];
            const float4 q1 = parts[par][1][0][j];
            const float4 q2 = parts[par][2][0][j];
            const float4 q3 = parts[par][3][0][j];
            const float gi = q0.x + q1.x + q2.x + q3.x + bg0;
            const float gf = q0.y + q1.y + q2.y + q3.y + bg1;
            const float gg = q0.z + q1.z + q2.z + q3.z + bg2;
            const float go = q0.w + q1.w + q2.w + q3.w + bg3;
            c0 = fmaf(sigf(gf), c0, sigf(gi) * tanhx(gg));
            h0 = sigf(go) * tanhx(c0);
        }
        {
            const float4 q0 = parts[par][0][1][j];
            const float4 q1 = parts[par][1][1][j];
            const float4 q2 = parts[par][2][1][j];
            const float4 q3 = parts[par][3][1][j];
            const float gi = q0.x + q1.x + q2.x + q3.x + bg0;
            const float gf = q0.y + q1.y + q2.y + q3.y + bg1;
            const float gg = q0.z + q1.z + q2.z + q3.z + bg2;
            const float go = q0.w + q1.w + q2.w + q3.w + bg3;
            c1 = fmaf(sigf(gf), c1, sigf(gi) * tanhx(gg));
            h1 = sigf(go) * tanhx(c1);
        }

        // ---- y_{t-1} store (waves 2/3; partials were computed from h_{t-1}) ----
        if (t >= 1 && w >= 2 && j < OUTF) {
            const int r = w - 2;
            const float ys = yparts[par][0][r][j] + yparts[par][1][r][j]
                           + yparts[par][2][r][j] + yparts[par][3][r][j] + bo;
            __builtin_nontemporal_store(sigf(ys),
                &out[(r ? ob1 : ob0) + (size_t)(t - 1) * OUTF + j]);
        }
    }

    // ---- epilogue: y_{T-1} from h_{T-1} (registers) ----
    {
        const int h0b = __float_as_int(h0), h1b = __float_as_int(h1);
        v2f yac = {0.f, 0.f};
#pragma unroll
        for (int K = 0; K < 16; ++K) {
            const float hs0 = RLF(h0b, kbase + K);
            const float hs1 = RLF(h1b, kbase + K);
            yac += (v2f){hs0, hs1} * (v2f){woa[K], woa[K]};
        }
        yparts[0][w][0][j] = yac.x;
        yparts[0][w][1][j] = yac.y;
        __syncthreads();
        if (w >= 2 && j < OUTF) {
            const int r = w - 2;
            const float ys = yparts[0][0][r][j] + yparts[0][1][r][j]
                           + yparts[0][2][r][j] + yparts[0][3][r][j] + bo;
            __builtin_nontemporal_store(sigf(ys),
                &out[(r ? ob1 : ob0) + (size_t)(TT - 1) * OUTF + j]);
        }
    }
}

extern "C" void kernel_launch(void* const* d_in, const int* in_sizes, int n_in,
                              void* d_out, int out_size, void* d_ws, size_t ws_size,
                              hipStream_t stream) {
    (void)in_sizes; (void)n_in; (void)out_size;
    const float* x     = (const float*)d_in[0];
    const float* W_ih  = (const float*)d_in[1];
    const float* W_hh  = (const float*)d_in[2];
    const float* b_ih  = (const float*)d_in[3];
    const float* b_hh  = (const float*)d_in[4];
    const float* W_out = (const float*)d_in[5];
    const float* b_out = (const float*)d_in[6];
    float* out = (float*)d_out;

    float4* wsq = (float4*)d_ws;
    const bool packed = (wsq != nullptr) && (ws_size >= (size_t)6656 * sizeof(float4));

    if (packed) {
        pack_weights<<<dim3(26), dim3(256), 0, stream>>>(W_ih, W_hh, wsq);
        lstm_1bar<true><<<dim3(BB / 2), dim3(256), 0, stream>>>(
            x, W_ih, W_hh, b_ih, b_hh, W_out, b_out, wsq, out);
    } else {
        lstm_1bar<false><<<dim3(BB / 2), dim3(256), 0, stream>>>(
            x, W_ih, W_hh, b_ih, b_hh, W_out, b_out, nullptr, out);
    }
}